// Round 29
// baseline (128.475 us; speedup 1.0000x reference)
//
#include <hip/hip_runtime.h>
#include <hip/hip_bf16.h>

// HPBC step — R26 structure (R=2 adjacent + tap sharing + pk-FMA + ±m shared
// G/H + template FIR + static double buffers + parity-split gh) with sE/sF
// stored as BF16 in LDS: 27.8 KB -> 5 blocks/CU (20 waves), conflict-free
// e-reads, halved sE/sF LDS bytes. gh stays f32 (accuracy + no unpack in FIR).
// Geometry (solved): dict inputs, true complex assembly; output chunks
// [E' | Eo], element storage (IMAG, REAL) per (b, i', pol); nout=65436, lpad=50.

namespace {

constexpr int NSEQ    = 65536;
constexpr int BATCH   = 8;
constexpr int KTAPS   = 449;
constexpr int NM      = 25;
constexpr int THREADS = 256;
constexpr int TILE    = 512;
constexpr int WIN     = TILE + 4 * NM;           // 612
constexpr int GHW     = TILE + 2 * NM + 1;       // 563
constexpr int GHH     = 282;                     // per parity array

typedef float v2f __attribute__((ext_vector_type(2)));

__device__ inline v2f pkfma(float s, v2f v, v2f acc) {
  return __builtin_elementwise_fma((v2f){s, s}, v, acc);
}

__device__ inline void mac(v2f& U13, v2f& U42, v2f& V13, v2f& V42,
                           const float4 c, const float4 g) {
  const v2f glo = (v2f){g.x, g.y}, ghi = (v2f){g.z, g.w};
  U13 = pkfma(c.x, glo, U13); U42 = pkfma(c.y, glo, U42);
  V13 = pkfma(c.z, ghi, V13); V42 = pkfma(c.w, ghi, V42);
}

__device__ inline unsigned short f2bf(float f) {
  __hip_bfloat16 h = __float2bfloat16(f);
  union { __hip_bfloat16 hh; unsigned short u; } cv;
  cv.hh = h;
  return cv.u;
}

__device__ inline float bfu2f(unsigned short s) {
  union { unsigned int u; float f; } c;
  c.u = (unsigned int)s << 16;
  return c.f;
}

__device__ inline ushort4 st4(float4 v) {
  ushort4 r;
  r.x = f2bf(v.x); r.y = f2bf(v.y); r.z = f2bf(v.z); r.w = f2bf(v.w);
  return r;
}

__device__ inline float4 ld4(const ushort4 v) {
  return make_float4(bfu2f(v.x), bfu2f(v.y), bfu2f(v.z), bfu2f(v.w));
}

// cw[row*K+k] = (c1r,c1i,c2r,c2i); cw[4K + row*K+k] = (c2r,c2i,c1r,c1i)
__global__ void prep_c_kernel(const float* __restrict__ c1r, const float* __restrict__ c1i,
                              const float* __restrict__ c2r, const float* __restrict__ c2i,
                              float4* __restrict__ cw) {
  int idx = blockIdx.x * blockDim.x + threadIdx.x;
  if (idx < 4 * KTAPS) {
    cw[idx]             = make_float4(c1r[idx], c1i[idx], c2r[idx], c2i[idx]);
    cw[4 * KTAPS + idx] = make_float4(c2r[idx], c2i[idx], c1r[idx], c1i[idx]);
  }
}

__device__ inline float4 gh_entry(const float4 e, const float4 f,
                                  const float4 fm, const float4 em) {
  v2f G = (v2f){fm.w * e.w, fm.w * (-e.z)};
  G = pkfma(fm.x, (v2f){e.x, e.y}, G);
  G = pkfma(fm.y, (v2f){e.y, -e.x}, G);
  G = pkfma(fm.z, (v2f){e.z, e.w}, G);
  v2f H = (v2f){em.w * f.w, em.w * (-f.z)};
  H = pkfma(em.x, (v2f){f.x, f.y}, H);
  H = pkfma(em.y, (v2f){f.y, -f.x}, H);
  H = pkfma(em.z, (v2f){f.z, f.w}, H);
  return make_float4(G.x, G.y, H.x, H.y);
}

template<int NMAX>
__device__ inline void fir_core(const float4* __restrict__ hiArr,
                                const float4* __restrict__ loArr,
                                int h0, int h1,
                                const float4* __restrict__ cc,
                                v2f& aU13, v2f& aU42, v2f& aV13, v2f& aV42,
                                v2f& bU13, v2f& bU42, v2f& bV13, v2f& bV42)
{
  float4 cOdd;
  {
    const float4 hi = hiArr[h0], lo = loArr[h1];
    const float4 c0 = cc[0], c1 = cc[1];
    mac(bU13, bU42, bV13, bV42, c0, hi);
    mac(bU13, bU42, bV13, bV42, c1, lo);
    mac(aU13, aU42, aV13, aV42, c0, lo);
    cOdd = c1;
  }
#pragma unroll
  for (int s = 1; s < NMAX; ++s) {
    const float4 hi = hiArr[h0 - s], lo = loArr[h1 - s];
    const float4 c2 = cc[2*s], c3 = cc[2*s + 1];
    mac(bU13, bU42, bV13, bV42, c2, hi);
    mac(bU13, bU42, bV13, bV42, c3, lo);
    mac(aU13, aU42, aV13, aV42, cOdd, hi);
    mac(aU13, aU42, aV13, aV42, c2, lo);
    cOdd = c3;
  }
  {
    const float4 hi = hiArr[h0 - NMAX], lo = loArr[h1 - NMAX];
    const float4 c2 = cc[2*NMAX];
    mac(bU13, bU42, bV13, bV42, c2, hi);
    mac(aU13, aU42, aV13, aV42, cOdd, hi);
    mac(aU13, aU42, aV13, aV42, c2, lo);
  }
}

#define FIR_SWITCH(NMX, HI, LO, H0, H1, CC) \
  switch (NMX) { \
    case 25: fir_core<25>(HI, LO, H0, H1, CC, U13a,U42a,V13a,V42a, U13b,U42b,V13b,V42b); break; \
    case 12: fir_core<12>(HI, LO, H0, H1, CC, U13a,U42a,V13a,V42a, U13b,U42b,V13b,V42b); break; \
    case  8: fir_core< 8>(HI, LO, H0, H1, CC, U13a,U42a,V13a,V42a, U13b,U42b,V13b,V42b); break; \
    case  6: fir_core< 6>(HI, LO, H0, H1, CC, U13a,U42a,V13a,V42a, U13b,U42b,V13b,V42b); break; \
    case  5: fir_core< 5>(HI, LO, H0, H1, CC, U13a,U42a,V13a,V42a, U13b,U42b,V13b,V42b); break; \
    case  4: fir_core< 4>(HI, LO, H0, H1, CC, U13a,U42a,V13a,V42a, U13b,U42b,V13b,V42b); break; \
    case  3: fir_core< 3>(HI, LO, H0, H1, CC, U13a,U42a,V13a,V42a, U13b,U42b,V13b,V42b); break; \
    case  2: fir_core< 2>(HI, LO, H0, H1, CC, U13a,U42a,V13a,V42a, U13b,U42b,V13b,V42b); break; \
    default: fir_core< 1>(HI, LO, H0, H1, CC, U13a,U42a,V13a,V42a, U13b,U42b,V13b,V42b); break; \
  }

__global__ __launch_bounds__(THREADS, 5) void hpbc_kernel(
    const float2* __restrict__ er, const float2* __restrict__ ei,
    const float2* __restrict__ fr, const float2* __restrict__ fi,
    const float*  __restrict__ task, const float4* __restrict__ cw,
    unsigned short* __restrict__ out, int nout, int lpad, int ntiles)
{
  __shared__ ushort4 sE[WIN];          // bf16x4: (p0.re, p0.im, p1.re, p1.im)
  __shared__ ushort4 sF[WIN];
  __shared__ float4 ghE0[GHH], ghO0[GHH];
  __shared__ float4 ghE1[GHH], ghO1[GHH];

  const int bx   = blockIdx.x;
  const int b    = bx / ntiles;
  const int tile = bx - b * ntiles;
  const int tid  = threadIdx.x;
  const int i0   = lpad + tile * TILE;
  const int elo  = i0 - 2 * NM;

  const float2* erb = er + (size_t)b * NSEQ;
  const float2* eib = ei + (size_t)b * NSEQ;
  const float2* frb = fr + (size_t)b * NSEQ;
  const float2* fib = fi + (size_t)b * NSEQ;

  for (int u = tid; u < WIN; u += THREADS) {
    int g = (elo + u) & (NSEQ - 1);                  // exact jnp.roll wrap
    float2 a = erb[g], c = eib[g];
    sE[u] = st4(make_float4(a.x, c.x, a.y, c.y));
    float2 d = frb[g], e = fib[g];
    sF[u] = st4(make_float4(d.x, e.x, d.y, e.y));
  }

  const float dbm = task[b * 4 + 0];
  const float fsr = task[b * 4 + 2];
  const int   x   = (int)(fsr / 2.0e9f);
  const int ind = (x == 40) ? 1 : (x == 80) ? 2 : (x == 160) ? 3 : 0;
  const float4* __restrict__ crow = cw + ind * KTAPS;
  const float4* __restrict__ cswp = cw + 4 * KTAPS + ind * KTAPS;
  const float P  = powf(10.0f, dbm * 0.1f) * 0.5f;
  const float pf = P * sqrtf(P);

  __syncthreads();

  // Unshifted E/F for this thread's gh entries (bi = tid, tid+256, tid+512).
  const float4 e0 = ld4(sE[tid + NM]),            f0 = ld4(sF[tid + NM]);
  const float4 e1 = ld4(sE[tid + THREADS + NM]),  f1 = ld4(sF[tid + THREADS + NM]);
  const bool  has3 = (tid < GHW - 2 * THREADS);   // tid < 51
  float4 e2 = make_float4(0,0,0,0), f2 = e2;
  if (has3) { e2 = ld4(sE[tid + 2*THREADS + NM]); f2 = ld4(sF[tid + 2*THREADS + NM]); }

  auto write_gh = [&](float4* wE, float4* wO, int Mn) {
    const int s = NM - Mn;
    const float4 g0 = gh_entry(e0, f0, ld4(sF[tid + s]), ld4(sE[tid + s]));
    if (tid & 1) wO[tid >> 1] = g0; else wE[tid >> 1] = g0;
    const float4 g1 = gh_entry(e1, f1, ld4(sF[tid + THREADS + s]), ld4(sE[tid + THREADS + s]));
    if (tid & 1) wO[(tid + THREADS) >> 1] = g1; else wE[(tid + THREADS) >> 1] = g1;
    if (has3) {
      const float4 g2 = gh_entry(e2, f2, ld4(sF[tid + 2*THREADS + s]), ld4(sE[tid + 2*THREADS + s]));
      if (tid & 1) wO[(tid + 2*THREADS) >> 1] = g2; else wE[(tid + 2*THREADS) >> 1] = g2;
    }
  };

  v2f A0 = {0,0}, A1 = {0,0}, B0 = {0,0}, B1 = {0,0};
  int kbaseP = 199;          // +m rows: m=0 at 199, ascending
  int kbaseN = 199;          // -m rows: row -M starts at kbaseN - T(M)
  float4 carry_p = ld4(sE[2*tid + 2*NM + 1]);
  float4 carry_m = carry_p;

  auto iter = [&](const float4* rE, const float4* rO,
                  float4* wE, float4* wO, int M) {
    const int nmax = (M == 0) ? NM : (NM / M);
    const int T    = 2 * nmax + 1;

    // ---- FIR(+M) ----
    {
      const int q = nmax & 1;
      const float4* hiArr = q ? rO : rE;
      const float4* loArr = q ? rE : rO;
      const int h0 = tid + ((26 + nmax) >> 1);
      const int h1 = tid + ((25 + nmax) >> 1);
      const float4* cc = crow + kbaseP;
      v2f U13a={0,0},U42a={0,0},V13a={0,0},V42a={0,0};
      v2f U13b={0,0},U42b={0,0},V13b={0,0},V42b={0,0};
      FIR_SWITCH(nmax, hiArr, loArr, h0, h1, cc);
      const float sra = U13a.x - U42a.y + V13a.x - V42a.y;
      const float sia = U13a.y + U42a.x + V13a.y + V42a.x;
      const float srb = U13b.x - U42b.y + V13b.x - V42b.y;
      const float sib = U13b.y + U42b.x + V13b.y + V42b.x;
      const float4 ea = ld4(sE[2*tid + 2*NM - M]);   // E[i-M]
      const float4 eb = carry_p;                     // E[i+1-M] = prev ea
      carry_p = ea;
      A0 = pkfma(sra, (v2f){ea.x, ea.y}, pkfma(sia, (v2f){-ea.y, ea.x}, A0));
      A1 = pkfma(sra, (v2f){ea.z, ea.w}, pkfma(sia, (v2f){-ea.w, ea.z}, A1));
      B0 = pkfma(srb, (v2f){eb.x, eb.y}, pkfma(sib, (v2f){-eb.y, eb.x}, B0));
      B1 = pkfma(srb, (v2f){eb.z, eb.w}, pkfma(sib, (v2f){-eb.w, eb.z}, B1));
    }
    kbaseP += T;

    // ---- FIR(-M): same buffer, base +M, swapped-c + conj reduction ----
    if (M > 0) {
      kbaseN -= T;
      const int qm = (M + nmax) & 1;
      const float4* hiArr = qm ? rO : rE;
      const float4* loArr = qm ? rE : rO;
      const int h0 = tid + ((26 + M + nmax) >> 1);
      const int h1 = tid + ((25 + M + nmax) >> 1);
      const float4* cc = cswp + kbaseN;
      v2f U13a={0,0},U42a={0,0},V13a={0,0},V42a={0,0};
      v2f U13b={0,0},U42b={0,0},V13b={0,0},V42b={0,0};
      FIR_SWITCH(nmax, hiArr, loArr, h0, h1, cc);
      const float sra = U13a.x + U42a.y + V13a.x + V42a.y;
      const float sia = U42a.x - U13a.y + V42a.x - V13a.y;
      const float srb = U13b.x + U42b.y + V13b.x + V42b.y;
      const float sib = U42b.x - U13b.y + V42b.x - V13b.y;
      const float4 ea = carry_m;                         // E[i+M]
      const float4 eb = ld4(sE[2*tid + 2*NM + 1 + M]);   // E[i+1+M]
      carry_m = eb;
      A0 = pkfma(sra, (v2f){ea.x, ea.y}, pkfma(sia, (v2f){-ea.y, ea.x}, A0));
      A1 = pkfma(sra, (v2f){ea.z, ea.w}, pkfma(sia, (v2f){-ea.w, ea.z}, A1));
      B0 = pkfma(srb, (v2f){eb.x, eb.y}, pkfma(sib, (v2f){-eb.y, eb.x}, B0));
      B1 = pkfma(srb, (v2f){eb.z, eb.w}, pkfma(sib, (v2f){-eb.w, eb.z}, B1));
    }

    // ---- GH(|m|=M+1) into the other buffer ----
    if (M < NM) write_gh(wE, wO, M + 1);

    __syncthreads();
  };

  // Prologue: GH(0) into buffer 0.
  write_gh(ghE0, ghO0, 0);
  __syncthreads();

  for (int M = 0; M <= NM; M += 2) {
    iter(ghE0, ghO0, ghE1, ghO1, M);           // even M: read buf0, write buf1
    if (M + 1 <= NM)
      iter(ghE1, ghO1, ghE0, ghO0, M + 1);     // odd M: read buf1, write buf0
  }

  // ---- Epilogue: (IMAG, REAL) element order ----
  const int end = lpad + nout;
  const size_t chunk1 = (size_t)BATCH * nout * 4;
  const int i = i0 + 2 * tid;
  if (i + 1 < end) {
    const ushort4 euA = sE[2*tid + 2*NM];      // already bf16; reorder bits
    const ushort4 euB = sE[2*tid + 1 + 2*NM];
    const float4 fvA = ld4(sF[2*tid + 2*NM]);
    const float4 fvB = ld4(sF[2*tid + 1 + 2*NM]);
    const size_t o = ((size_t)b * nout + (size_t)(i - lpad)) * 4;
    ushort4 w0a, w0b, w1a, w1b;
    w0a.x = euA.y; w0a.y = euA.x; w0a.z = euA.w; w0a.w = euA.z;
    w0b.x = euB.y; w0b.y = euB.x; w0b.z = euB.w; w0b.w = euB.z;
    w1a.x = f2bf(fvA.y + pf * A0.y); w1a.y = f2bf(fvA.x + pf * A0.x);
    w1a.z = f2bf(fvA.w + pf * A1.y); w1a.w = f2bf(fvA.z + pf * A1.x);
    w1b.x = f2bf(fvB.y + pf * B0.y); w1b.y = f2bf(fvB.x + pf * B0.x);
    w1b.z = f2bf(fvB.w + pf * B1.y); w1b.w = f2bf(fvB.z + pf * B1.x);
    *reinterpret_cast<ushort4*>(out + o) = w0a;
    *reinterpret_cast<ushort4*>(out + o + 4) = w0b;
    *reinterpret_cast<ushort4*>(out + chunk1 + o) = w1a;
    *reinterpret_cast<ushort4*>(out + chunk1 + o + 4) = w1b;
  } else if (i < end) {
    const ushort4 euA = sE[2*tid + 2*NM];
    const float4 fvA = ld4(sF[2*tid + 2*NM]);
    const size_t o = ((size_t)b * nout + (size_t)(i - lpad)) * 4;
    ushort4 w0a, w1a;
    w0a.x = euA.y; w0a.y = euA.x; w0a.z = euA.w; w0a.w = euA.z;
    w1a.x = f2bf(fvA.y + pf * A0.y); w1a.y = f2bf(fvA.x + pf * A0.x);
    w1a.z = f2bf(fvA.w + pf * A1.y); w1a.w = f2bf(fvA.z + pf * A1.x);
    *reinterpret_cast<ushort4*>(out + o) = w0a;
    *reinterpret_cast<ushort4*>(out + chunk1 + o) = w1a;
  }
}

} // namespace

extern "C" void kernel_launch(void* const* d_in, const int* in_sizes, int n_in,
                              void* d_out, int out_size, void* d_ws, size_t ws_size,
                              hipStream_t stream) {
  const float* E_real  = (const float*)d_in[0];
  const float* E_imag  = (const float*)d_in[1];
  const float* F_real  = (const float*)d_in[2];
  const float* F_imag  = (const float*)d_in[3];
  const float* C1_real = (const float*)d_in[4];
  const float* C1_imag = (const float*)d_in[5];
  const float* C2_real = (const float*)d_in[6];
  const float* C2_imag = (const float*)d_in[7];
  const float* task    = (const float*)d_in[8];

  int nout = out_size / 32;
  if (nout < 1 || nout > NSEQ) nout = NSEQ - 100;
  const int lpad   = (NSEQ - nout) / 2;             // 50
  const int ntiles = (nout + TILE - 1) / TILE;      // 128

  unsigned short* outp = (unsigned short*)d_out;
  float4* cw = (float4*)d_ws;                       // 2 tables: 57,472 B

  hipLaunchKernelGGL(prep_c_kernel, dim3((4 * KTAPS + 255) / 256), dim3(256), 0, stream,
                     C1_real, C1_imag, C2_real, C2_imag, cw);

  hipLaunchKernelGGL(hpbc_kernel, dim3(BATCH * ntiles), dim3(THREADS), 0, stream,
                     (const float2*)E_real, (const float2*)E_imag,
                     (const float2*)F_real, (const float2*)F_imag,
                     task, cw, outp, nout, lpad, ntiles);
}

// Round 30
// 83.081 us; speedup vs baseline: 1.5464x; 1.5464x over previous
//
#include <hip/hip_runtime.h>
#include <hip/hip_bf16.h>

// HPBC step — R26 structure (R=2 adjacent + tap sharing + pk-FMA + ±m shared
// G/H + template FIR + static double buffers + parity-split gh) with sE/sF
// stored as BF16 in LDS (27.8 KB -> 5 blocks/CU by LDS), launch_bounds(256,4)
// (R29's bound of 5 caused catastrophic scratch spills: WRITE_SIZE 68 MB).
// Geometry (solved): dict inputs, true complex assembly; output chunks
// [E' | Eo], element storage (IMAG, REAL) per (b, i', pol); nout=65436, lpad=50.

namespace {

constexpr int NSEQ    = 65536;
constexpr int BATCH   = 8;
constexpr int KTAPS   = 449;
constexpr int NM      = 25;
constexpr int THREADS = 256;
constexpr int TILE    = 512;
constexpr int WIN     = TILE + 4 * NM;           // 612
constexpr int GHW     = TILE + 2 * NM + 1;       // 563
constexpr int GHH     = 282;                     // per parity array

typedef float v2f __attribute__((ext_vector_type(2)));

__device__ inline v2f pkfma(float s, v2f v, v2f acc) {
  return __builtin_elementwise_fma((v2f){s, s}, v, acc);
}

__device__ inline void mac(v2f& U13, v2f& U42, v2f& V13, v2f& V42,
                           const float4 c, const float4 g) {
  const v2f glo = (v2f){g.x, g.y}, ghi = (v2f){g.z, g.w};
  U13 = pkfma(c.x, glo, U13); U42 = pkfma(c.y, glo, U42);
  V13 = pkfma(c.z, ghi, V13); V42 = pkfma(c.w, ghi, V42);
}

__device__ inline unsigned short f2bf(float f) {
  __hip_bfloat16 h = __float2bfloat16(f);
  union { __hip_bfloat16 hh; unsigned short u; } cv;
  cv.hh = h;
  return cv.u;
}

__device__ inline float bfu2f(unsigned short s) {
  union { unsigned int u; float f; } c;
  c.u = (unsigned int)s << 16;
  return c.f;
}

__device__ inline ushort4 st4(float4 v) {
  ushort4 r;
  r.x = f2bf(v.x); r.y = f2bf(v.y); r.z = f2bf(v.z); r.w = f2bf(v.w);
  return r;
}

__device__ inline float4 ld4(const ushort4 v) {
  return make_float4(bfu2f(v.x), bfu2f(v.y), bfu2f(v.z), bfu2f(v.w));
}

// cw[row*K+k] = (c1r,c1i,c2r,c2i); cw[4K + row*K+k] = (c2r,c2i,c1r,c1i)
__global__ void prep_c_kernel(const float* __restrict__ c1r, const float* __restrict__ c1i,
                              const float* __restrict__ c2r, const float* __restrict__ c2i,
                              float4* __restrict__ cw) {
  int idx = blockIdx.x * blockDim.x + threadIdx.x;
  if (idx < 4 * KTAPS) {
    cw[idx]             = make_float4(c1r[idx], c1i[idx], c2r[idx], c2i[idx]);
    cw[4 * KTAPS + idx] = make_float4(c2r[idx], c2i[idx], c1r[idx], c1i[idx]);
  }
}

__device__ inline float4 gh_entry(const float4 e, const float4 f,
                                  const float4 fm, const float4 em) {
  v2f G = (v2f){fm.w * e.w, fm.w * (-e.z)};
  G = pkfma(fm.x, (v2f){e.x, e.y}, G);
  G = pkfma(fm.y, (v2f){e.y, -e.x}, G);
  G = pkfma(fm.z, (v2f){e.z, e.w}, G);
  v2f H = (v2f){em.w * f.w, em.w * (-f.z)};
  H = pkfma(em.x, (v2f){f.x, f.y}, H);
  H = pkfma(em.y, (v2f){f.y, -f.x}, H);
  H = pkfma(em.z, (v2f){f.z, f.w}, H);
  return make_float4(G.x, G.y, H.x, H.y);
}

template<int NMAX>
__device__ inline void fir_core(const float4* __restrict__ hiArr,
                                const float4* __restrict__ loArr,
                                int h0, int h1,
                                const float4* __restrict__ cc,
                                v2f& aU13, v2f& aU42, v2f& aV13, v2f& aV42,
                                v2f& bU13, v2f& bU42, v2f& bV13, v2f& bV42)
{
  float4 cOdd;
  {
    const float4 hi = hiArr[h0], lo = loArr[h1];
    const float4 c0 = cc[0], c1 = cc[1];
    mac(bU13, bU42, bV13, bV42, c0, hi);
    mac(bU13, bU42, bV13, bV42, c1, lo);
    mac(aU13, aU42, aV13, aV42, c0, lo);
    cOdd = c1;
  }
#pragma unroll
  for (int s = 1; s < NMAX; ++s) {
    const float4 hi = hiArr[h0 - s], lo = loArr[h1 - s];
    const float4 c2 = cc[2*s], c3 = cc[2*s + 1];
    mac(bU13, bU42, bV13, bV42, c2, hi);
    mac(bU13, bU42, bV13, bV42, c3, lo);
    mac(aU13, aU42, aV13, aV42, cOdd, hi);
    mac(aU13, aU42, aV13, aV42, c2, lo);
    cOdd = c3;
  }
  {
    const float4 hi = hiArr[h0 - NMAX], lo = loArr[h1 - NMAX];
    const float4 c2 = cc[2*NMAX];
    mac(bU13, bU42, bV13, bV42, c2, hi);
    mac(aU13, aU42, aV13, aV42, cOdd, hi);
    mac(aU13, aU42, aV13, aV42, c2, lo);
  }
}

#define FIR_SWITCH(NMX, HI, LO, H0, H1, CC) \
  switch (NMX) { \
    case 25: fir_core<25>(HI, LO, H0, H1, CC, U13a,U42a,V13a,V42a, U13b,U42b,V13b,V42b); break; \
    case 12: fir_core<12>(HI, LO, H0, H1, CC, U13a,U42a,V13a,V42a, U13b,U42b,V13b,V42b); break; \
    case  8: fir_core< 8>(HI, LO, H0, H1, CC, U13a,U42a,V13a,V42a, U13b,U42b,V13b,V42b); break; \
    case  6: fir_core< 6>(HI, LO, H0, H1, CC, U13a,U42a,V13a,V42a, U13b,U42b,V13b,V42b); break; \
    case  5: fir_core< 5>(HI, LO, H0, H1, CC, U13a,U42a,V13a,V42a, U13b,U42b,V13b,V42b); break; \
    case  4: fir_core< 4>(HI, LO, H0, H1, CC, U13a,U42a,V13a,V42a, U13b,U42b,V13b,V42b); break; \
    case  3: fir_core< 3>(HI, LO, H0, H1, CC, U13a,U42a,V13a,V42a, U13b,U42b,V13b,V42b); break; \
    case  2: fir_core< 2>(HI, LO, H0, H1, CC, U13a,U42a,V13a,V42a, U13b,U42b,V13b,V42b); break; \
    default: fir_core< 1>(HI, LO, H0, H1, CC, U13a,U42a,V13a,V42a, U13b,U42b,V13b,V42b); break; \
  }

__global__ __launch_bounds__(THREADS, 4) void hpbc_kernel(
    const float2* __restrict__ er, const float2* __restrict__ ei,
    const float2* __restrict__ fr, const float2* __restrict__ fi,
    const float*  __restrict__ task, const float4* __restrict__ cw,
    unsigned short* __restrict__ out, int nout, int lpad, int ntiles)
{
  __shared__ ushort4 sE[WIN];          // bf16x4: (p0.re, p0.im, p1.re, p1.im)
  __shared__ ushort4 sF[WIN];
  __shared__ float4 ghE0[GHH], ghO0[GHH];
  __shared__ float4 ghE1[GHH], ghO1[GHH];

  const int bx   = blockIdx.x;
  const int b    = bx / ntiles;
  const int tile = bx - b * ntiles;
  const int tid  = threadIdx.x;
  const int i0   = lpad + tile * TILE;
  const int elo  = i0 - 2 * NM;

  const float2* erb = er + (size_t)b * NSEQ;
  const float2* eib = ei + (size_t)b * NSEQ;
  const float2* frb = fr + (size_t)b * NSEQ;
  const float2* fib = fi + (size_t)b * NSEQ;

  for (int u = tid; u < WIN; u += THREADS) {
    int g = (elo + u) & (NSEQ - 1);                  // exact jnp.roll wrap
    float2 a = erb[g], c = eib[g];
    sE[u] = st4(make_float4(a.x, c.x, a.y, c.y));
    float2 d = frb[g], e = fib[g];
    sF[u] = st4(make_float4(d.x, e.x, d.y, e.y));
  }

  const float dbm = task[b * 4 + 0];
  const float fsr = task[b * 4 + 2];
  const int   x   = (int)(fsr / 2.0e9f);
  const int ind = (x == 40) ? 1 : (x == 80) ? 2 : (x == 160) ? 3 : 0;
  const float4* __restrict__ crow = cw + ind * KTAPS;
  const float4* __restrict__ cswp = cw + 4 * KTAPS + ind * KTAPS;
  const float P  = powf(10.0f, dbm * 0.1f) * 0.5f;
  const float pf = P * sqrtf(P);

  __syncthreads();

  // Unshifted E/F for this thread's gh entries (bi = tid, tid+256, tid+512).
  const float4 e0 = ld4(sE[tid + NM]),            f0 = ld4(sF[tid + NM]);
  const float4 e1 = ld4(sE[tid + THREADS + NM]),  f1 = ld4(sF[tid + THREADS + NM]);
  const bool  has3 = (tid < GHW - 2 * THREADS);   // tid < 51
  float4 e2 = make_float4(0,0,0,0), f2 = e2;
  if (has3) { e2 = ld4(sE[tid + 2*THREADS + NM]); f2 = ld4(sF[tid + 2*THREADS + NM]); }

  auto write_gh = [&](float4* wE, float4* wO, int Mn) {
    const int s = NM - Mn;
    const float4 g0 = gh_entry(e0, f0, ld4(sF[tid + s]), ld4(sE[tid + s]));
    if (tid & 1) wO[tid >> 1] = g0; else wE[tid >> 1] = g0;
    const float4 g1 = gh_entry(e1, f1, ld4(sF[tid + THREADS + s]), ld4(sE[tid + THREADS + s]));
    if (tid & 1) wO[(tid + THREADS) >> 1] = g1; else wE[(tid + THREADS) >> 1] = g1;
    if (has3) {
      const float4 g2 = gh_entry(e2, f2, ld4(sF[tid + 2*THREADS + s]), ld4(sE[tid + 2*THREADS + s]));
      if (tid & 1) wO[(tid + 2*THREADS) >> 1] = g2; else wE[(tid + 2*THREADS) >> 1] = g2;
    }
  };

  v2f A0 = {0,0}, A1 = {0,0}, B0 = {0,0}, B1 = {0,0};
  int kbaseP = 199;          // +m rows: m=0 at 199, ascending
  int kbaseN = 199;          // -m rows: row -M starts at kbaseN - T(M)
  float4 carry_p = ld4(sE[2*tid + 2*NM + 1]);
  float4 carry_m = carry_p;

  auto iter = [&](const float4* rE, const float4* rO,
                  float4* wE, float4* wO, int M) {
    const int nmax = (M == 0) ? NM : (NM / M);
    const int T    = 2 * nmax + 1;

    // ---- FIR(+M) ----
    {
      const int q = nmax & 1;
      const float4* hiArr = q ? rO : rE;
      const float4* loArr = q ? rE : rO;
      const int h0 = tid + ((26 + nmax) >> 1);
      const int h1 = tid + ((25 + nmax) >> 1);
      const float4* cc = crow + kbaseP;
      v2f U13a={0,0},U42a={0,0},V13a={0,0},V42a={0,0};
      v2f U13b={0,0},U42b={0,0},V13b={0,0},V42b={0,0};
      FIR_SWITCH(nmax, hiArr, loArr, h0, h1, cc);
      const float sra = U13a.x - U42a.y + V13a.x - V42a.y;
      const float sia = U13a.y + U42a.x + V13a.y + V42a.x;
      const float srb = U13b.x - U42b.y + V13b.x - V42b.y;
      const float sib = U13b.y + U42b.x + V13b.y + V42b.x;
      const float4 ea = ld4(sE[2*tid + 2*NM - M]);   // E[i-M]
      const float4 eb = carry_p;                     // E[i+1-M] = prev ea
      carry_p = ea;
      A0 = pkfma(sra, (v2f){ea.x, ea.y}, pkfma(sia, (v2f){-ea.y, ea.x}, A0));
      A1 = pkfma(sra, (v2f){ea.z, ea.w}, pkfma(sia, (v2f){-ea.w, ea.z}, A1));
      B0 = pkfma(srb, (v2f){eb.x, eb.y}, pkfma(sib, (v2f){-eb.y, eb.x}, B0));
      B1 = pkfma(srb, (v2f){eb.z, eb.w}, pkfma(sib, (v2f){-eb.w, eb.z}, B1));
    }
    kbaseP += T;

    // ---- FIR(-M): same buffer, base +M, swapped-c + conj reduction ----
    if (M > 0) {
      kbaseN -= T;
      const int qm = (M + nmax) & 1;
      const float4* hiArr = qm ? rO : rE;
      const float4* loArr = qm ? rE : rO;
      const int h0 = tid + ((26 + M + nmax) >> 1);
      const int h1 = tid + ((25 + M + nmax) >> 1);
      const float4* cc = cswp + kbaseN;
      v2f U13a={0,0},U42a={0,0},V13a={0,0},V42a={0,0};
      v2f U13b={0,0},U42b={0,0},V13b={0,0},V42b={0,0};
      FIR_SWITCH(nmax, hiArr, loArr, h0, h1, cc);
      const float sra = U13a.x + U42a.y + V13a.x + V42a.y;
      const float sia = U42a.x - U13a.y + V42a.x - V13a.y;
      const float srb = U13b.x + U42b.y + V13b.x + V42b.y;
      const float sib = U42b.x - U13b.y + V42b.x - V13b.y;
      const float4 ea = carry_m;                         // E[i+M]
      const float4 eb = ld4(sE[2*tid + 2*NM + 1 + M]);   // E[i+1+M]
      carry_m = eb;
      A0 = pkfma(sra, (v2f){ea.x, ea.y}, pkfma(sia, (v2f){-ea.y, ea.x}, A0));
      A1 = pkfma(sra, (v2f){ea.z, ea.w}, pkfma(sia, (v2f){-ea.w, ea.z}, A1));
      B0 = pkfma(srb, (v2f){eb.x, eb.y}, pkfma(sib, (v2f){-eb.y, eb.x}, B0));
      B1 = pkfma(srb, (v2f){eb.z, eb.w}, pkfma(sib, (v2f){-eb.w, eb.z}, B1));
    }

    // ---- GH(|m|=M+1) into the other buffer ----
    if (M < NM) write_gh(wE, wO, M + 1);

    __syncthreads();
  };

  // Prologue: GH(0) into buffer 0.
  write_gh(ghE0, ghO0, 0);
  __syncthreads();

  for (int M = 0; M <= NM; M += 2) {
    iter(ghE0, ghO0, ghE1, ghO1, M);           // even M: read buf0, write buf1
    if (M + 1 <= NM)
      iter(ghE1, ghO1, ghE0, ghO0, M + 1);     // odd M: read buf1, write buf0
  }

  // ---- Epilogue: (IMAG, REAL) element order ----
  const int end = lpad + nout;
  const size_t chunk1 = (size_t)BATCH * nout * 4;
  const int i = i0 + 2 * tid;
  if (i + 1 < end) {
    const ushort4 euA = sE[2*tid + 2*NM];      // already bf16; reorder
    const ushort4 euB = sE[2*tid + 1 + 2*NM];
    const float4 fvA = ld4(sF[2*tid + 2*NM]);
    const float4 fvB = ld4(sF[2*tid + 1 + 2*NM]);
    const size_t o = ((size_t)b * nout + (size_t)(i - lpad)) * 4;
    ushort4 w0a, w0b, w1a, w1b;
    w0a.x = euA.y; w0a.y = euA.x; w0a.z = euA.w; w0a.w = euA.z;
    w0b.x = euB.y; w0b.y = euB.x; w0b.z = euB.w; w0b.w = euB.z;
    w1a.x = f2bf(fvA.y + pf * A0.y); w1a.y = f2bf(fvA.x + pf * A0.x);
    w1a.z = f2bf(fvA.w + pf * A1.y); w1a.w = f2bf(fvA.z + pf * A1.x);
    w1b.x = f2bf(fvB.y + pf * B0.y); w1b.y = f2bf(fvB.x + pf * B0.x);
    w1b.z = f2bf(fvB.w + pf * B1.y); w1b.w = f2bf(fvB.z + pf * B1.x);
    *reinterpret_cast<ushort4*>(out + o) = w0a;
    *reinterpret_cast<ushort4*>(out + o + 4) = w0b;
    *reinterpret_cast<ushort4*>(out + chunk1 + o) = w1a;
    *reinterpret_cast<ushort4*>(out + chunk1 + o + 4) = w1b;
  } else if (i < end) {
    const ushort4 euA = sE[2*tid + 2*NM];
    const float4 fvA = ld4(sF[2*tid + 2*NM]);
    const size_t o = ((size_t)b * nout + (size_t)(i - lpad)) * 4;
    ushort4 w0a, w1a;
    w0a.x = euA.y; w0a.y = euA.x; w0a.z = euA.w; w0a.w = euA.z;
    w1a.x = f2bf(fvA.y + pf * A0.y); w1a.y = f2bf(fvA.x + pf * A0.x);
    w1a.z = f2bf(fvA.w + pf * A1.y); w1a.w = f2bf(fvA.z + pf * A1.x);
    *reinterpret_cast<ushort4*>(out + o) = w0a;
    *reinterpret_cast<ushort4*>(out + chunk1 + o) = w1a;
  }
}

} // namespace

extern "C" void kernel_launch(void* const* d_in, const int* in_sizes, int n_in,
                              void* d_out, int out_size, void* d_ws, size_t ws_size,
                              hipStream_t stream) {
  const float* E_real  = (const float*)d_in[0];
  const float* E_imag  = (const float*)d_in[1];
  const float* F_real  = (const float*)d_in[2];
  const float* F_imag  = (const float*)d_in[3];
  const float* C1_real = (const float*)d_in[4];
  const float* C1_imag = (const float*)d_in[5];
  const float* C2_real = (const float*)d_in[6];
  const float* C2_imag = (const float*)d_in[7];
  const float* task    = (const float*)d_in[8];

  int nout = out_size / 32;
  if (nout < 1 || nout > NSEQ) nout = NSEQ - 100;
  const int lpad   = (NSEQ - nout) / 2;             // 50
  const int ntiles = (nout + TILE - 1) / TILE;      // 128

  unsigned short* outp = (unsigned short*)d_out;
  float4* cw = (float4*)d_ws;                       // 2 tables: 57,472 B

  hipLaunchKernelGGL(prep_c_kernel, dim3((4 * KTAPS + 255) / 256), dim3(256), 0, stream,
                     C1_real, C1_imag, C2_real, C2_imag, cw);

  hipLaunchKernelGGL(hpbc_kernel, dim3(BATCH * ntiles), dim3(THREADS), 0, stream,
                     (const float2*)E_real, (const float2*)E_imag,
                     (const float2*)F_real, (const float2*)F_imag,
                     task, cw, outp, nout, lpad, ntiles);
}

// Round 31
// 80.546 us; speedup vs baseline: 1.5951x; 1.0315x over previous
//
#include <hip/hip_runtime.h>
#include <hip/hip_bf16.h>

// HPBC step — FINAL (revert to R26, the empirical best at 80.0 us):
// R=2 adjacent outputs + tap sharing + pk-FMA + ±m shared G/H
// (G_{-m}[j]=conj(H_m[j+m])) + template<NMAX> fully-unrolled FIR + statically
// named double buffers + parity-split gh (conflict-free FIR reads).
// Geometry (solved): dict inputs, true complex assembly; output chunks
// [E' | Eo], element storage (IMAG, REAL) per (b, i', pol); nout=65436, lpad=50.
// Post-R26 attempts all regressed: loop rotation (null), R=4 (spill/occupancy),
// bf16-LDS (spills at 5 blocks/CU; VALU-tax at 4) — dual-pipe floor reached.

namespace {

constexpr int NSEQ    = 65536;
constexpr int BATCH   = 8;
constexpr int KTAPS   = 449;
constexpr int NM      = 25;
constexpr int THREADS = 256;
constexpr int TILE    = 512;
constexpr int WIN     = TILE + 4 * NM;           // 612
constexpr int GHW     = TILE + 2 * NM + 1;       // 563
constexpr int GHH     = 282;                     // per parity array

typedef float v2f __attribute__((ext_vector_type(2)));

__device__ inline v2f pkfma(float s, v2f v, v2f acc) {
  return __builtin_elementwise_fma((v2f){s, s}, v, acc);
}

__device__ inline void mac(v2f& U13, v2f& U42, v2f& V13, v2f& V42,
                           const float4 c, const float4 g) {
  const v2f glo = (v2f){g.x, g.y}, ghi = (v2f){g.z, g.w};
  U13 = pkfma(c.x, glo, U13); U42 = pkfma(c.y, glo, U42);
  V13 = pkfma(c.z, ghi, V13); V42 = pkfma(c.w, ghi, V42);
}

__device__ inline unsigned short f2bf(float f) {
  __hip_bfloat16 h = __float2bfloat16(f);
  union { __hip_bfloat16 hh; unsigned short u; } cv;
  cv.hh = h;
  return cv.u;
}

// cw[row*K+k] = (c1r,c1i,c2r,c2i); cw[4K + row*K+k] = (c2r,c2i,c1r,c1i)
__global__ void prep_c_kernel(const float* __restrict__ c1r, const float* __restrict__ c1i,
                              const float* __restrict__ c2r, const float* __restrict__ c2i,
                              float4* __restrict__ cw) {
  int idx = blockIdx.x * blockDim.x + threadIdx.x;
  if (idx < 4 * KTAPS) {
    cw[idx]             = make_float4(c1r[idx], c1i[idx], c2r[idx], c2i[idx]);
    cw[4 * KTAPS + idx] = make_float4(c2r[idx], c2i[idx], c1r[idx], c1i[idx]);
  }
}

__device__ inline float4 gh_entry(const float4 e, const float4 f,
                                  const float4 fm, const float4 em) {
  v2f G = (v2f){fm.w * e.w, fm.w * (-e.z)};
  G = pkfma(fm.x, (v2f){e.x, e.y}, G);
  G = pkfma(fm.y, (v2f){e.y, -e.x}, G);
  G = pkfma(fm.z, (v2f){e.z, e.w}, G);
  v2f H = (v2f){em.w * f.w, em.w * (-f.z)};
  H = pkfma(em.x, (v2f){f.x, f.y}, H);
  H = pkfma(em.y, (v2f){f.y, -f.x}, H);
  H = pkfma(em.z, (v2f){f.z, f.w}, H);
  return make_float4(G.x, G.y, H.x, H.y);
}

template<int NMAX>
__device__ inline void fir_core(const float4* __restrict__ hiArr,
                                const float4* __restrict__ loArr,
                                int h0, int h1,
                                const float4* __restrict__ cc,
                                v2f& aU13, v2f& aU42, v2f& aV13, v2f& aV42,
                                v2f& bU13, v2f& bU42, v2f& bV13, v2f& bV42)
{
  float4 cOdd;
  {
    const float4 hi = hiArr[h0], lo = loArr[h1];
    const float4 c0 = cc[0], c1 = cc[1];
    mac(bU13, bU42, bV13, bV42, c0, hi);
    mac(bU13, bU42, bV13, bV42, c1, lo);
    mac(aU13, aU42, aV13, aV42, c0, lo);
    cOdd = c1;
  }
#pragma unroll
  for (int s = 1; s < NMAX; ++s) {
    const float4 hi = hiArr[h0 - s], lo = loArr[h1 - s];
    const float4 c2 = cc[2*s], c3 = cc[2*s + 1];
    mac(bU13, bU42, bV13, bV42, c2, hi);
    mac(bU13, bU42, bV13, bV42, c3, lo);
    mac(aU13, aU42, aV13, aV42, cOdd, hi);
    mac(aU13, aU42, aV13, aV42, c2, lo);
    cOdd = c3;
  }
  {
    const float4 hi = hiArr[h0 - NMAX], lo = loArr[h1 - NMAX];
    const float4 c2 = cc[2*NMAX];
    mac(bU13, bU42, bV13, bV42, c2, hi);
    mac(aU13, aU42, aV13, aV42, cOdd, hi);
    mac(aU13, aU42, aV13, aV42, c2, lo);
  }
}

#define FIR_SWITCH(NMX, HI, LO, H0, H1, CC) \
  switch (NMX) { \
    case 25: fir_core<25>(HI, LO, H0, H1, CC, U13a,U42a,V13a,V42a, U13b,U42b,V13b,V42b); break; \
    case 12: fir_core<12>(HI, LO, H0, H1, CC, U13a,U42a,V13a,V42a, U13b,U42b,V13b,V42b); break; \
    case  8: fir_core< 8>(HI, LO, H0, H1, CC, U13a,U42a,V13a,V42a, U13b,U42b,V13b,V42b); break; \
    case  6: fir_core< 6>(HI, LO, H0, H1, CC, U13a,U42a,V13a,V42a, U13b,U42b,V13b,V42b); break; \
    case  5: fir_core< 5>(HI, LO, H0, H1, CC, U13a,U42a,V13a,V42a, U13b,U42b,V13b,V42b); break; \
    case  4: fir_core< 4>(HI, LO, H0, H1, CC, U13a,U42a,V13a,V42a, U13b,U42b,V13b,V42b); break; \
    case  3: fir_core< 3>(HI, LO, H0, H1, CC, U13a,U42a,V13a,V42a, U13b,U42b,V13b,V42b); break; \
    case  2: fir_core< 2>(HI, LO, H0, H1, CC, U13a,U42a,V13a,V42a, U13b,U42b,V13b,V42b); break; \
    default: fir_core< 1>(HI, LO, H0, H1, CC, U13a,U42a,V13a,V42a, U13b,U42b,V13b,V42b); break; \
  }

__global__ __launch_bounds__(THREADS, 4) void hpbc_kernel(
    const float2* __restrict__ er, const float2* __restrict__ ei,
    const float2* __restrict__ fr, const float2* __restrict__ fi,
    const float*  __restrict__ task, const float4* __restrict__ cw,
    unsigned short* __restrict__ out, int nout, int lpad, int ntiles)
{
  __shared__ float4 sE[WIN];
  __shared__ float4 sF[WIN];
  __shared__ float4 ghE0[GHH], ghO0[GHH];
  __shared__ float4 ghE1[GHH], ghO1[GHH];

  const int bx   = blockIdx.x;
  const int b    = bx / ntiles;
  const int tile = bx - b * ntiles;
  const int tid  = threadIdx.x;
  const int i0   = lpad + tile * TILE;
  const int elo  = i0 - 2 * NM;

  const float2* erb = er + (size_t)b * NSEQ;
  const float2* eib = ei + (size_t)b * NSEQ;
  const float2* frb = fr + (size_t)b * NSEQ;
  const float2* fib = fi + (size_t)b * NSEQ;

  for (int u = tid; u < WIN; u += THREADS) {
    int g = (elo + u) & (NSEQ - 1);                  // exact jnp.roll wrap
    float2 a = erb[g], c = eib[g];
    sE[u] = make_float4(a.x, c.x, a.y, c.y);
    float2 d = frb[g], e = fib[g];
    sF[u] = make_float4(d.x, e.x, d.y, e.y);
  }

  const float dbm = task[b * 4 + 0];
  const float fsr = task[b * 4 + 2];
  const int   x   = (int)(fsr / 2.0e9f);
  const int ind = (x == 40) ? 1 : (x == 80) ? 2 : (x == 160) ? 3 : 0;
  const float4* __restrict__ crow = cw + ind * KTAPS;
  const float4* __restrict__ cswp = cw + 4 * KTAPS + ind * KTAPS;
  const float P  = powf(10.0f, dbm * 0.1f) * 0.5f;
  const float pf = P * sqrtf(P);

  __syncthreads();

  // Unshifted E/F for this thread's gh entries (bi = tid, tid+256, tid+512).
  const float4 e0 = sE[tid + NM],            f0 = sF[tid + NM];
  const float4 e1 = sE[tid + THREADS + NM],  f1 = sF[tid + THREADS + NM];
  const bool  has3 = (tid < GHW - 2 * THREADS);   // tid < 51
  float4 e2 = make_float4(0,0,0,0), f2 = e2;
  if (has3) { e2 = sE[tid + 2*THREADS + NM]; f2 = sF[tid + 2*THREADS + NM]; }

  auto write_gh = [&](float4* wE, float4* wO, int Mn) {
    const int s = NM - Mn;
    const float4 g0 = gh_entry(e0, f0, sF[tid + s], sE[tid + s]);
    if (tid & 1) wO[tid >> 1] = g0; else wE[tid >> 1] = g0;
    const float4 g1 = gh_entry(e1, f1, sF[tid + THREADS + s], sE[tid + THREADS + s]);
    if (tid & 1) wO[(tid + THREADS) >> 1] = g1; else wE[(tid + THREADS) >> 1] = g1;
    if (has3) {
      const float4 g2 = gh_entry(e2, f2, sF[tid + 2*THREADS + s], sE[tid + 2*THREADS + s]);
      if (tid & 1) wO[(tid + 2*THREADS) >> 1] = g2; else wE[(tid + 2*THREADS) >> 1] = g2;
    }
  };

  v2f A0 = {0,0}, A1 = {0,0}, B0 = {0,0}, B1 = {0,0};
  int kbaseP = 199;          // +m rows: m=0 at 199, ascending
  int kbaseN = 199;          // -m rows: row -M starts at kbaseN - T(M)
  float4 carry_p = sE[2*tid + 2*NM + 1];
  float4 carry_m = carry_p;

  auto iter = [&](const float4* rE, const float4* rO,
                  float4* wE, float4* wO, int M) {
    const int nmax = (M == 0) ? NM : (NM / M);
    const int T    = 2 * nmax + 1;

    // ---- FIR(+M) ----
    {
      const int q = nmax & 1;
      const float4* hiArr = q ? rO : rE;
      const float4* loArr = q ? rE : rO;
      const int h0 = tid + ((26 + nmax) >> 1);
      const int h1 = tid + ((25 + nmax) >> 1);
      const float4* cc = crow + kbaseP;
      v2f U13a={0,0},U42a={0,0},V13a={0,0},V42a={0,0};
      v2f U13b={0,0},U42b={0,0},V13b={0,0},V42b={0,0};
      FIR_SWITCH(nmax, hiArr, loArr, h0, h1, cc);
      const float sra = U13a.x - U42a.y + V13a.x - V42a.y;
      const float sia = U13a.y + U42a.x + V13a.y + V42a.x;
      const float srb = U13b.x - U42b.y + V13b.x - V42b.y;
      const float sib = U13b.y + U42b.x + V13b.y + V42b.x;
      const float4 ea = sE[2*tid + 2*NM - M];    // E[i-M]
      const float4 eb = carry_p;                 // E[i+1-M] = prev ea
      carry_p = ea;
      A0 = pkfma(sra, (v2f){ea.x, ea.y}, pkfma(sia, (v2f){-ea.y, ea.x}, A0));
      A1 = pkfma(sra, (v2f){ea.z, ea.w}, pkfma(sia, (v2f){-ea.w, ea.z}, A1));
      B0 = pkfma(srb, (v2f){eb.x, eb.y}, pkfma(sib, (v2f){-eb.y, eb.x}, B0));
      B1 = pkfma(srb, (v2f){eb.z, eb.w}, pkfma(sib, (v2f){-eb.w, eb.z}, B1));
    }
    kbaseP += T;

    // ---- FIR(-M): same buffer, base +M, swapped-c + conj reduction ----
    if (M > 0) {
      kbaseN -= T;
      const int qm = (M + nmax) & 1;
      const float4* hiArr = qm ? rO : rE;
      const float4* loArr = qm ? rE : rO;
      const int h0 = tid + ((26 + M + nmax) >> 1);
      const int h1 = tid + ((25 + M + nmax) >> 1);
      const float4* cc = cswp + kbaseN;
      v2f U13a={0,0},U42a={0,0},V13a={0,0},V42a={0,0};
      v2f U13b={0,0},U42b={0,0},V13b={0,0},V42b={0,0};
      FIR_SWITCH(nmax, hiArr, loArr, h0, h1, cc);
      const float sra = U13a.x + U42a.y + V13a.x + V42a.y;
      const float sia = U42a.x - U13a.y + V42a.x - V13a.y;
      const float srb = U13b.x + U42b.y + V13b.x + V42b.y;
      const float sib = U42b.x - U13b.y + V42b.x - V13b.y;
      const float4 ea = carry_m;                       // E[i+M] = prev eb_minus
      const float4 eb = sE[2*tid + 2*NM + 1 + M];      // E[i+1+M]
      carry_m = eb;
      A0 = pkfma(sra, (v2f){ea.x, ea.y}, pkfma(sia, (v2f){-ea.y, ea.x}, A0));
      A1 = pkfma(sra, (v2f){ea.z, ea.w}, pkfma(sia, (v2f){-ea.w, ea.z}, A1));
      B0 = pkfma(srb, (v2f){eb.x, eb.y}, pkfma(sib, (v2f){-eb.y, eb.x}, B0));
      B1 = pkfma(srb, (v2f){eb.z, eb.w}, pkfma(sib, (v2f){-eb.w, eb.z}, B1));
    }

    // ---- GH(|m|=M+1) into the other buffer ----
    if (M < NM) write_gh(wE, wO, M + 1);

    __syncthreads();
  };

  // Prologue: GH(0) into buffer 0.
  write_gh(ghE0, ghO0, 0);
  __syncthreads();

  for (int M = 0; M <= NM; M += 2) {
    iter(ghE0, ghO0, ghE1, ghO1, M);           // even M: read buf0, write buf1
    if (M + 1 <= NM)
      iter(ghE1, ghO1, ghE0, ghO0, M + 1);     // odd M: read buf1, write buf0
  }

  // ---- Epilogue: (IMAG, REAL) element order ----
  const int end = lpad + nout;
  const size_t chunk1 = (size_t)BATCH * nout * 4;
  const int i = i0 + 2 * tid;
  if (i + 1 < end) {
    const float4 evA = sE[2*tid + 2*NM],     fvA = sF[2*tid + 2*NM];
    const float4 evB = sE[2*tid + 1 + 2*NM], fvB = sF[2*tid + 1 + 2*NM];
    const size_t o = ((size_t)b * nout + (size_t)(i - lpad)) * 4;
    ushort4 w0a, w0b, w1a, w1b;
    w0a.x = f2bf(evA.y); w0a.y = f2bf(evA.x); w0a.z = f2bf(evA.w); w0a.w = f2bf(evA.z);
    w0b.x = f2bf(evB.y); w0b.y = f2bf(evB.x); w0b.z = f2bf(evB.w); w0b.w = f2bf(evB.z);
    w1a.x = f2bf(fvA.y + pf * A0.y); w1a.y = f2bf(fvA.x + pf * A0.x);
    w1a.z = f2bf(fvA.w + pf * A1.y); w1a.w = f2bf(fvA.z + pf * A1.x);
    w1b.x = f2bf(fvB.y + pf * B0.y); w1b.y = f2bf(fvB.x + pf * B0.x);
    w1b.z = f2bf(fvB.w + pf * B1.y); w1b.w = f2bf(fvB.z + pf * B1.x);
    *reinterpret_cast<ushort4*>(out + o) = w0a;
    *reinterpret_cast<ushort4*>(out + o + 4) = w0b;
    *reinterpret_cast<ushort4*>(out + chunk1 + o) = w1a;
    *reinterpret_cast<ushort4*>(out + chunk1 + o + 4) = w1b;
  } else if (i < end) {
    const float4 evA = sE[2*tid + 2*NM], fvA = sF[2*tid + 2*NM];
    const size_t o = ((size_t)b * nout + (size_t)(i - lpad)) * 4;
    ushort4 w0a, w1a;
    w0a.x = f2bf(evA.y); w0a.y = f2bf(evA.x); w0a.z = f2bf(evA.w); w0a.w = f2bf(evA.z);
    w1a.x = f2bf(fvA.y + pf * A0.y); w1a.y = f2bf(fvA.x + pf * A0.x);
    w1a.z = f2bf(fvA.w + pf * A1.y); w1a.w = f2bf(fvA.z + pf * A1.x);
    *reinterpret_cast<ushort4*>(out + o) = w0a;
    *reinterpret_cast<ushort4*>(out + chunk1 + o) = w1a;
  }
}

} // namespace

extern "C" void kernel_launch(void* const* d_in, const int* in_sizes, int n_in,
                              void* d_out, int out_size, void* d_ws, size_t ws_size,
                              hipStream_t stream) {
  const float* E_real  = (const float*)d_in[0];
  const float* E_imag  = (const float*)d_in[1];
  const float* F_real  = (const float*)d_in[2];
  const float* F_imag  = (const float*)d_in[3];
  const float* C1_real = (const float*)d_in[4];
  const float* C1_imag = (const float*)d_in[5];
  const float* C2_real = (const float*)d_in[6];
  const float* C2_imag = (const float*)d_in[7];
  const float* task    = (const float*)d_in[8];

  int nout = out_size / 32;
  if (nout < 1 || nout > NSEQ) nout = NSEQ - 100;
  const int lpad   = (NSEQ - nout) / 2;             // 50
  const int ntiles = (nout + TILE - 1) / TILE;      // 128

  unsigned short* outp = (unsigned short*)d_out;
  float4* cw = (float4*)d_ws;                       // 2 tables: 57,472 B

  hipLaunchKernelGGL(prep_c_kernel, dim3((4 * KTAPS + 255) / 256), dim3(256), 0, stream,
                     C1_real, C1_imag, C2_real, C2_imag, cw);

  hipLaunchKernelGGL(hpbc_kernel, dim3(BATCH * ntiles), dim3(THREADS), 0, stream,
                     (const float2*)E_real, (const float2*)E_imag,
                     (const float2*)F_real, (const float2*)F_imag,
                     task, cw, outp, nout, lpad, ntiles);
}